// Round 2
// baseline (4462.939 us; speedup 1.0000x reference)
//
#include <hip/hip_runtime.h>
#include <cstdint>

// ---------------- static config ----------------
#define KFS 144   // padded feature stride for Qf/Kf (129 real + zeros)

// workspace offsets (in floats)
constexpr size_t o_wcat  = 0;                               // [768][448] proj weights concat
constexpr size_t o_wcat2 = o_wcat  + (size_t)768*448;       // [832][68]  Whd | Wdec_head | pad
constexpr size_t o_key   = o_wcat2 + (size_t)832*68;        // [B][T][1024][64]
constexpr size_t o_ms    = o_key   + (size_t)2*16*1024*64;  // [B][T][1024]
constexpr size_t o_qe    = o_ms    + (size_t)2*16*1024;     // [B][T][1024][64]
constexpr size_t o_f16   = o_qe    + (size_t)2*16*1024*64;  // [B][T][1024][256]
constexpr size_t o_qf    = o_f16   + (size_t)2*16*1024*256; // [B][T][1024][KFS]
constexpr size_t o_kf    = o_qf    + (size_t)2*16*1024*KFS; // [B][3072][KFS]
constexpr size_t o_v     = o_kf    + (size_t)2*3072*KFS;    // [B][3072][512]
constexpr size_t o_s     = o_v     + (size_t)2*3072*512;    // [B][1024][3072]
constexpr size_t o_rst   = o_s     + (size_t)2*1024*3072;   // [B][1024][2] (max,sum)
constexpr size_t o_r     = o_rst   + (size_t)2*1024*2;      // [B][5][1024][512]
constexpr size_t o_hid   = o_r     + (size_t)2*5*1024*512;  // [B][1024][64]
constexpr size_t o_wmk   = o_hid   + (size_t)2*1024*64;     // [B][1024]
constexpr size_t o_facc  = o_wmk   + (size_t)2*1024;        // [B][T][72]
constexpr size_t ws_need = o_facc  + (size_t)2*16*72;

// ---------------- init: weight concats + zero accumulators ----------------
extern "C" __global__ __launch_bounds__(256)
void k_init(const float* __restrict__ Wk, const float* __restrict__ Wsh,
            const float* __restrict__ Wse, const float* __restrict__ Wf,
            const float* __restrict__ Whd, const float* __restrict__ Wdec,
            float* __restrict__ wcat, float* __restrict__ wcat2, float* __restrict__ facc)
{
    int idx = blockIdx.x*256 + threadIdx.x;
    const int R0 = 768*448, R1 = 832*68, R2 = 2*16*72;
    if (idx < R0) {
        int k = idx/448, n = idx%448;
        float v;
        if (n < 64)       v = Wk[k*64+n];
        else if (n == 64) v = Wsh[k];
        else if (n < 129) v = Wse[k*64 + (n-65)];
        else if (n < 385) v = Wf[k*256 + (n-129)];
        else              v = 0.f;
        wcat[idx] = v;
    } else if (idx < R0+R1) {
        int i2 = idx - R0;
        int k = i2/68, c = i2%68;
        float v = 0.f;
        if (c < 64)       v = Whd[k*64+c];
        else if (c == 64) v = (k < 768) ? Wdec[k] : 0.f;
        wcat2[i2] = v;
    } else if (idx < R0+R1+R2) {
        facc[idx - R0 - R1] = 0.f;
    }
}

// ---------------- projection GEMM with fused patchify A-load ----------------
// grid (7, 16, B*T), block 256. C[1024,448] = patches[1024,768] @ wcat[768,448]
extern "C" __global__ __launch_bounds__(256)
void k_proj(const float* __restrict__ frames, const float* __restrict__ wcat,
            float* __restrict__ key, float* __restrict__ ms,
            float* __restrict__ qe, float* __restrict__ f16)
{
    const int bt = blockIdx.z;
    const int n0 = blockIdx.x*64, p0 = blockIdx.y*64;
    const int tid = threadIdx.x, tx = tid & 15, ty = tid >> 4;
    __shared__ float As[16][68], Bs[16][68];
    float acc[4][4] = {};
    const float* fb = frames + (size_t)bt*3*262144;
    const int kk = tid & 15, rr = tid >> 4;
    const int colB = tid & 63, kB = tid >> 6;
    for (int k0 = 0; k0 < 768; k0 += 16) {
        int k = k0 + kk;
        int c = k >> 8, rem = k & 255, pi = rem >> 4, pj = rem & 15;
        const float* fc = fb + (size_t)c*262144 + pi*512 + pj;
        #pragma unroll
        for (int s = 0; s < 4; s++) {
            int row = rr + s*16, p = p0 + row;
            int i = p >> 5, j = p & 31;
            As[kk][row] = fc[i*16*512 + j*16];
        }
        #pragma unroll
        for (int s = 0; s < 4; s++) {
            int kb2 = kB + s*4;
            Bs[kb2][colB] = wcat[(size_t)(k0+kb2)*448 + n0 + colB];
        }
        __syncthreads();
        #pragma unroll
        for (int q = 0; q < 16; q++) {
            float4 av = *(const float4*)&As[q][ty*4];
            float4 bv = *(const float4*)&Bs[q][tx*4];
            float a_[4] = {av.x,av.y,av.z,av.w};
            float b_[4] = {bv.x,bv.y,bv.z,bv.w};
            #pragma unroll
            for (int i=0;i<4;i++)
                #pragma unroll
                for (int j=0;j<4;j++)
                    acc[i][j] = fmaf(a_[i], b_[j], acc[i][j]);
        }
        __syncthreads();
    }
    #pragma unroll
    for (int i=0;i<4;i++) {
        int p = p0 + ty*4 + i;
        size_t rowb = (size_t)bt*1024 + p;
        #pragma unroll
        for (int j=0;j<4;j++) {
            int n = n0 + tx*4 + j;
            float v = acc[i][j];
            if (n < 64)       key[rowb*64 + n] = v;
            else if (n == 64) ms[rowb] = v*v + 1.f;
            else if (n < 129) qe[rowb*64 + (n-65)] = 1.f/(1.f+expf(-v));
            else if (n < 385) f16[rowb*256 + (n-129)] = v;
        }
    }
}

// ---------------- build Qfeat [qe*qk | qe | b_sq | 0-pad] ----------------
// grid (B*T, 128), block (64,8)
extern "C" __global__ __launch_bounds__(512)
void k_qf(const float* __restrict__ key, const float* __restrict__ qe, float* __restrict__ qf)
{
    int bt = blockIdx.x;
    int p = blockIdx.y*8 + threadIdx.y;
    int c = threadIdx.x;
    size_t rowb = (size_t)bt*1024 + p;
    float qk = key[rowb*64 + c];
    float qv = qe[rowb*64 + c];
    float bsq = qv*qk*qk;
    #pragma unroll
    for (int off=32; off; off>>=1) bsq += __shfl_xor(bsq, off);
    float* q = qf + rowb*KFS;
    q[c] = qv*qk;
    q[64+c] = qv;
    if (c == 0) q[128] = bsq;
    if (c < 15) q[129+c] = 0.f;
}

// ---------------- t=0 mask: aggregate + 16x16 avg-pool ----------------
// grid 8, block 256 (one thread per (b,p))
extern "C" __global__ __launch_bounds__(256)
void k_mask0(const float* __restrict__ im, float* __restrict__ wmask)
{
    int idx = blockIdx.x*256+threadIdx.x;
    int b = idx>>10, p = idx&1023;
    int i = p>>5, j = p&31;
    const float* mb = im + (size_t)b*262144 + (size_t)(i*16)*512 + j*16;
    float s=0.f;
    for (int pi=0; pi<16; pi++)
        for (int pj=0; pj<16; pj++){
            float m = mb[pi*512+pj];
            float p1 = fminf(fmaxf(m,      1e-7f), 1.f-1e-7f);
            float q1 = fminf(fmaxf(1.f-m,  1e-7f), 1.f-1e-7f);
            float l1 = logf(p1/(1.f-p1));
            float l0 = logf(q1/(1.f-q1));
            s += 1.f/(1.f+expf(l0-l1));
        }
    wmask[idx] = s*(1.f/256.f);
}

// ---------------- value GEMM: V[slot] = f16[t] @ Wv[0:256] + wmask*Wv[256] ----------------
// grid (8, 16, B), block 256
extern "C" __global__ __launch_bounds__(256)
void k_value(const float* __restrict__ f16, const float* __restrict__ wmask,
             const float* __restrict__ Wv, float* __restrict__ V, int t, int slot)
{
    int b = blockIdx.z;
    int n0 = blockIdx.x*64, p0 = blockIdx.y*64;
    int tid = threadIdx.x, tx = tid&15, ty = tid>>4;
    __shared__ float As[16][68], Bs[16][68];
    float acc[4][4] = {};
    const float* A = f16 + ((size_t)(b*16+t)*1024)*256;
    const int kk=tid&15, rr=tid>>4, colB=tid&63, kB=tid>>6;
    for (int k0=0;k0<256;k0+=16) {
        #pragma unroll
        for (int s=0;s<4;s++){ int row=rr+s*16; As[kk][row] = A[(size_t)(p0+row)*256 + k0+kk]; }
        #pragma unroll
        for (int s=0;s<4;s++){ int kb2=kB+s*4; Bs[kb2][colB] = Wv[(size_t)(k0+kb2)*512 + n0+colB]; }
        __syncthreads();
        #pragma unroll
        for (int q = 0; q < 16; q++) {
            float4 av = *(const float4*)&As[q][ty*4];
            float4 bv = *(const float4*)&Bs[q][tx*4];
            float a_[4] = {av.x,av.y,av.z,av.w};
            float b_[4] = {bv.x,bv.y,bv.z,bv.w};
            #pragma unroll
            for (int i=0;i<4;i++)
                #pragma unroll
                for (int j=0;j<4;j++)
                    acc[i][j] = fmaf(a_[i], b_[j], acc[i][j]);
        }
        __syncthreads();
    }
    #pragma unroll
    for (int i=0;i<4;i++) {
        int p = p0 + ty*4 + i;
        float wm = wmask[b*1024 + p];
        #pragma unroll
        for (int j=0;j<4;j++) {
            int n = n0 + tx*4 + j;
            V[((size_t)b*3072 + slot*1024 + p)*512 + n] = acc[i][j] + wm*Wv[256*512 + n];
        }
    }
}

// ---------------- build Kfeat rows for a memory slot ----------------
// grid (B, 128), block (64,8)
extern "C" __global__ __launch_bounds__(512)
void k_kf(const float* __restrict__ key, const float* __restrict__ ms,
          float* __restrict__ kf, int tm, int slot)
{
    int b = blockIdx.x;
    int p = blockIdx.y*8 + threadIdx.y;
    int c = threadIdx.x;
    size_t rowb = (size_t)(b*16+tm)*1024 + p;
    float mk = key[rowb*64+c];
    float m  = ms[rowb];
    float* kr = kf + ((size_t)b*3072 + slot*1024 + p)*KFS;
    kr[c]     =  m*mk*0.25f;
    kr[64+c]  = -m*mk*mk*0.125f;
    if (c==0) kr[128] = -m*0.125f;
    if (c<15) kr[129+c] = 0.f;
}

// ---------------- hidden GEMM: hidden = tanh([V_slot | hidden?] @ Wh2) ----------------
// grid (1, 16, B), block 256
extern "C" __global__ __launch_bounds__(256)
void k_hid(const float* __restrict__ V, const float* __restrict__ Wh2,
           float* __restrict__ hidden, int vslot, int has_h)
{
    int b = blockIdx.z; int p0 = blockIdx.y*64;
    int tid=threadIdx.x, tx=tid&15, ty=tid>>4;
    __shared__ float As[16][68], Bs[16][68];
    float acc[4][4]={};
    const float* A  = V + ((size_t)b*3072 + vslot*1024)*512;
    const float* Hh = hidden + (size_t)b*1024*64;
    int KK = has_h ? 576 : 512;
    const int kk=tid&15, rr=tid>>4, colB=tid&63, kB=tid>>6;
    for (int k0=0;k0<KK;k0+=16) {
        #pragma unroll
        for (int s=0;s<4;s++) {
            int row=rr+s*16, p=p0+row, k=k0+kk;
            As[kk][row] = (k<512) ? A[(size_t)p*512 + k] : Hh[(size_t)p*64 + (k-512)];
        }
        #pragma unroll
        for (int s=0;s<4;s++){ int kb2=kB+s*4; Bs[kb2][colB] = Wh2[(size_t)(k0+kb2)*64 + colB]; }
        __syncthreads();
        #pragma unroll
        for (int q = 0; q < 16; q++) {
            float4 av = *(const float4*)&As[q][ty*4];
            float4 bv = *(const float4*)&Bs[q][tx*4];
            float a_[4] = {av.x,av.y,av.z,av.w};
            float b_[4] = {bv.x,bv.y,bv.z,bv.w};
            #pragma unroll
            for (int i=0;i<4;i++)
                #pragma unroll
                for (int j=0;j<4;j++)
                    acc[i][j] = fmaf(a_[i], b_[j], acc[i][j]);
        }
        __syncthreads();
    }
    #pragma unroll
    for (int i=0;i<4;i++){
        int p = p0+ty*4+i;
        #pragma unroll
        for (int j=0;j<4;j++)
            hidden[(size_t)(b*1024+p)*64 + tx*4+j] = tanhf(acc[i][j]);
    }
}

// ---------------- S = Qf @ Kf^T  (both K-contiguous) ----------------
// grid (N/64, 16, B), block 256
extern "C" __global__ __launch_bounds__(256)
void k_s(const float* __restrict__ qf, const float* __restrict__ kf,
         float* __restrict__ S, int t, int N)
{
    (void)N;
    int b = blockIdx.z; int n0 = blockIdx.x*64, p0 = blockIdx.y*64;
    int tid=threadIdx.x, tx=tid&15, ty=tid>>4;
    __shared__ float As[16][68], Bs[16][68];
    float acc[4][4]={};
    const float* A = qf + ((size_t)(b*16+t)*1024)*KFS;
    const float* B = kf + ((size_t)b*3072)*KFS;
    const int kk=tid&15, rr=tid>>4;
    for (int k0=0;k0<KFS;k0+=16) {
        #pragma unroll
        for (int s=0;s<4;s++){int row=rr+s*16; As[kk][row] = A[(size_t)(p0+row)*KFS + k0+kk];}
        #pragma unroll
        for (int s=0;s<4;s++){int col=rr+s*16; Bs[kk][col] = B[(size_t)(n0+col)*KFS + k0+kk];}
        __syncthreads();
        #pragma unroll
        for (int q = 0; q < 16; q++) {
            float4 av = *(const float4*)&As[q][ty*4];
            float4 bv = *(const float4*)&Bs[q][tx*4];
            float a_[4] = {av.x,av.y,av.z,av.w};
            float b_[4] = {bv.x,bv.y,bv.z,bv.w};
            #pragma unroll
            for (int i=0;i<4;i++)
                #pragma unroll
                for (int j=0;j<4;j++)
                    acc[i][j] = fmaf(a_[i], b_[j], acc[i][j]);
        }
        __syncthreads();
    }
    #pragma unroll
    for (int i=0;i<4;i++)
        #pragma unroll
        for (int j=0;j<4;j++)
            S[((size_t)b*1024 + p0+ty*4+i)*3072 + n0+tx*4+j] = acc[i][j];
}

// ---------------- row max/sum over N (online) ----------------
// grid (128, B), block (64,8)
extern "C" __global__ __launch_bounds__(512)
void k_stat(const float* __restrict__ S, float* __restrict__ rst, int N)
{
    int b = blockIdx.y; int p = blockIdx.x*8 + threadIdx.y; int lane = threadIdx.x;
    const float* srow = S + ((size_t)b*1024 + p)*3072;
    float m = -1e30f, s = 0.f;
    for (int n = lane; n < N; n += 64) {
        float x = srow[n];
        float mn = fmaxf(m, x);
        s = s*expf(m-mn) + expf(x-mn);
        m = mn;
    }
    #pragma unroll
    for (int off=1; off<64; off<<=1) {
        float m2 = __shfl_xor(m, off), s2 = __shfl_xor(s, off);
        float mn = fmaxf(m, m2);
        s = s*expf(m-mn) + s2*expf(m2-mn);
        m = mn;
    }
    if (lane == 0) { rst[((size_t)b*1024+p)*2] = m; rst[((size_t)b*1024+p)*2+1] = s; }
}

// ---------------- R = softmax(S) @ V  (exp fused into A-load, /sum in epilogue) ----------------
// grid (8, 16, B), block 256
extern "C" __global__ __launch_bounds__(256)
void k_r(const float* __restrict__ S, const float* __restrict__ rst,
         const float* __restrict__ V, float* __restrict__ R, int tslot, int N)
{
    int b = blockIdx.z; int n0 = blockIdx.x*64, p0 = blockIdx.y*64;
    int tid=threadIdx.x, tx=tid&15, ty=tid>>4;
    __shared__ float As[16][68], Bs[16][68];
    float acc[4][4]={};
    const float* Sb = S + ((size_t)b*1024)*3072;
    const float* Vb = V + ((size_t)b*3072)*512;
    const int kk=tid&15, rr=tid>>4, colB=tid&63, kB=tid>>6;
    float rm[4];
    #pragma unroll
    for (int s=0;s<4;s++) rm[s] = rst[((size_t)b*1024 + p0+rr+s*16)*2];
    for (int k0=0;k0<N;k0+=16) {
        #pragma unroll
        for (int s=0;s<4;s++){int row=rr+s*16; As[kk][row] = expf(Sb[(size_t)(p0+row)*3072 + k0+kk] - rm[s]);}
        #pragma unroll
        for (int s=0;s<4;s++){int kb2=kB+s*4; Bs[kb2][colB] = Vb[(size_t)(k0+kb2)*512 + n0+colB];}
        __syncthreads();
        #pragma unroll
        for (int q = 0; q < 16; q++) {
            float4 av = *(const float4*)&As[q][ty*4];
            float4 bv = *(const float4*)&Bs[q][tx*4];
            float a_[4] = {av.x,av.y,av.z,av.w};
            float b_[4] = {bv.x,bv.y,bv.z,bv.w};
            #pragma unroll
            for (int i=0;i<4;i++)
                #pragma unroll
                for (int j=0;j<4;j++)
                    acc[i][j] = fmaf(a_[i], b_[j], acc[i][j]);
        }
        __syncthreads();
    }
    #pragma unroll
    for (int i=0;i<4;i++) {
        int p = p0+ty*4+i;
        float rinv = 1.f / rst[((size_t)b*1024+p)*2+1];
        #pragma unroll
        for (int j=0;j<4;j++)
            R[(((size_t)b*5+tslot)*1024 + p)*512 + n0+tx*4+j] = acc[i][j]*rinv;
    }
}

// ---------------- row-local chain for a 5-step phase ----------------
// grid (32, B), block 256; 32 rows per block
extern "C" __global__ __launch_bounds__(256)
void k_chain(const float* __restrict__ f16, const float* __restrict__ Rbuf,
             const float* __restrict__ wcat2, const float* __restrict__ Wdec,
             float* __restrict__ hidden, float* __restrict__ wmask,
             float* __restrict__ facc, int t0)
{
    int b = blockIdx.y; int p0 = blockIdx.x*32;
    int tid = threadIdx.x, tx = tid&15, ty = tid>>4;
    __shared__ float As[16][36], Bs[16][68];
    __shared__ float hls[32][65], hid[32][65];
    __shared__ float fgh[32], mrow[32], wdt[64];
    for (int idx=tid; idx<32*64; idx+=256){int r=idx>>6,c=idx&63; hid[r][c]=hidden[((size_t)b*1024+p0+r)*64+c];}
    if (tid<64) wdt[tid] = Wdec[768+tid];
    __syncthreads();
    const int kk=tid&15, rr=tid>>4;
    for (int ts=0; ts<5; ts++) {
        int t = t0+ts;
        float acc[2][4]={}; float fgp[2]={};
        const float* Fr = f16  + ((size_t)(b*16+t)*1024)*256;
        const float* Rr = Rbuf + (((size_t)b*5+ts)*1024)*512;
        for (int kc=0;kc<52;kc++){
            int k0=kc*16, k=k0+kk;
            #pragma unroll
            for (int s=0;s<2;s++){
                int row = rr + s*16, p = p0+row;
                float v;
                if (k < 256)      v = Fr[(size_t)p*256 + k];
                else if (k < 768) v = Rr[(size_t)p*512 + (k-256)];
                else              v = hid[row][k-768];
                As[kk][row]=v;
            }
            for (int idx=tid; idx<16*68; idx+=256){int k2=idx/68, c2=idx%68; Bs[k2][c2]=wcat2[(size_t)(k0+k2)*68 + c2];}
            __syncthreads();
            #pragma unroll
            for (int q=0;q<16;q++){
                float2 av = *(const float2*)&As[q][ty*2];
                float4 bv = *(const float4*)&Bs[q][tx*4];
                float a_[2]={av.x,av.y}, b_[4]={bv.x,bv.y,bv.z,bv.w};
                #pragma unroll
                for (int i=0;i<2;i++)
                    #pragma unroll
                    for (int j=0;j<4;j++)
                        acc[i][j]=fmaf(a_[i],b_[j],acc[i][j]);
                if (tx==0){ float bd=Bs[q][64]; fgp[0]=fmaf(a_[0],bd,fgp[0]); fgp[1]=fmaf(a_[1],bd,fgp[1]); }
            }
            __syncthreads();
        }
        #pragma unroll
        for (int i=0;i<2;i++){
            int r=ty*2+i;
            #pragma unroll
            for (int j=0;j<4;j++) hls[r][tx*4+j]=tanhf(acc[i][j]);
        }
        if (tx==0){ fgh[ty*2]=fgp[0]; fgh[ty*2+1]=fgp[1]; }
        __syncthreads();
        if (tid<32){
            int r=tid; float s=fgh[r];
            for (int c=0;c<64;c++) s += hls[r][c]*wdt[c];
            float m = 1.f/(1.f+expf(-s));
            mrow[r]=m;
            if (t==5 || t==10) wmask[b*1024+p0+r]=m;
        }
        __syncthreads();
        if (tid<64){
            int c=tid; float s=0.f;
            for (int r=0;r<32;r++) s += mrow[r]*hls[r][c];
            atomicAdd(&facc[(b*16+t)*72+c], s);
        } else if (tid==64){
            float s=0.f; for (int r=0;r<32;r++) s+=mrow[r];
            atomicAdd(&facc[(b*16+t)*72+64], s);
        }
        __syncthreads();
        for (int idx=tid; idx<32*64; idx+=256){int r=idx>>6,c=idx&63; hid[r][c]=hls[r][c];}
        __syncthreads();
    }
    for (int idx=tid; idx<32*64; idx+=256){int r=idx>>6,c=idx&63; hidden[((size_t)b*1024+p0+r)*64+c]=hid[r][c];}
}

// ---------------- feat at t=0 (mean of key[0]) ----------------
extern "C" __global__ void k_feat0(const float* __restrict__ key, float* __restrict__ out)
{
    int b = blockIdx.x, c = threadIdx.x; // block 64
    const float* kb = key + (size_t)(b*16)*1024*64;
    float s=0.f;
    for (int p=0;p<1024;p++) s += kb[(size_t)p*64+c];
    out[(size_t)(b*16)*64 + c] = s*(1.f/1024.f);
}

// ---------------- finalize feats (divide by weight sum) ----------------
extern "C" __global__ void k_featdiv(const float* __restrict__ facc, float* __restrict__ out)
{
    int idx = blockIdx.x*256+threadIdx.x;
    if (idx >= 2*15*64) return;
    int b = idx/960, rem = idx%960;
    int t = 1 + rem/64, c = rem%64;
    const float* f = facc + (size_t)(b*16+t)*72;
    out[(size_t)(b*16+t)*64 + c] = f[c] / fmaxf(f[64], 1e-6f);
}

// ---------------- host launcher ----------------
extern "C" void kernel_launch(void* const* d_in, const int* in_sizes, int n_in,
                              void* d_out, int out_size, void* d_ws, size_t ws_size,
                              hipStream_t stream)
{
    (void)in_sizes; (void)n_in; (void)out_size;
    if (ws_size < ws_need*sizeof(float)) return;   // loud failure instead of corruption
    const float* frames = (const float*)d_in[0];
    const float* imask  = (const float*)d_in[1];
    const float* Wk  = (const float*)d_in[3];
    const float* Wsh = (const float*)d_in[4];
    const float* Wse = (const float*)d_in[5];
    const float* Wf  = (const float*)d_in[6];
    const float* Wv  = (const float*)d_in[7];
    const float* Wh2 = (const float*)d_in[8];
    const float* Whd = (const float*)d_in[9];
    const float* Wdec= (const float*)d_in[10];
    float* out = (float*)d_out;
    float* ws  = (float*)d_ws;
    float* wcat  = ws + o_wcat;
    float* wcat2 = ws + o_wcat2;
    float* key   = ws + o_key;
    float* ms    = ws + o_ms;
    float* qe    = ws + o_qe;
    float* f16   = ws + o_f16;
    float* qf    = ws + o_qf;
    float* kf    = ws + o_kf;
    float* v     = ws + o_v;
    float* sbuf  = ws + o_s;
    float* rst   = ws + o_rst;
    float* rbuf  = ws + o_r;
    float* hid   = ws + o_hid;
    float* wmk   = ws + o_wmk;
    float* facc  = ws + o_facc;

    k_init<<<1574,256,0,stream>>>(Wk,Wsh,Wse,Wf,Whd,Wdec,wcat,wcat2,facc);
    k_proj<<<dim3(7,16,32),256,0,stream>>>(frames,wcat,key,ms,qe,f16);
    k_qf<<<dim3(32,128),dim3(64,8),0,stream>>>(key,qe,qf);
    k_mask0<<<8,256,0,stream>>>(imask,wmk);
    k_value<<<dim3(8,16,2),256,0,stream>>>(f16,wmk,Wv,v,0,0);
    k_kf<<<dim3(2,128),dim3(64,8),0,stream>>>(key,ms,kf,0,0);
    k_hid<<<dim3(1,16,2),256,0,stream>>>(v,Wh2,hid,0,0);
    k_feat0<<<2,64,0,stream>>>(key,out);

    const int Ns[3] = {1024,2048,3072};
    for (int ph=0; ph<3; ph++){
        int t0 = 1+ph*5, N = Ns[ph];
        for (int ts=0; ts<5; ts++){
            int t = t0+ts;
            k_s   <<<dim3(N/64,16,2),256,0,stream>>>(qf,kf,sbuf,t,N);
            k_stat<<<dim3(128,2),dim3(64,8),0,stream>>>(sbuf,rst,N);
            k_r   <<<dim3(8,16,2),256,0,stream>>>(sbuf,rst,v,rbuf,ts,N);
        }
        k_chain<<<dim3(32,2),256,0,stream>>>(f16,rbuf,wcat2,Wdec,hid,wmk,facc,t0);
        if (ph<2){
            int tm=t0+4, slot=ph+1;
            k_value<<<dim3(8,16,2),256,0,stream>>>(f16,wmk,Wv,v,tm,slot);
            k_kf<<<dim3(2,128),dim3(64,8),0,stream>>>(key,ms,kf,tm,slot);
            if (ph==1) k_hid<<<dim3(1,16,2),256,0,stream>>>(v,Wh2,hid,2,1);
        }
    }
    k_featdiv<<<8,256,0,stream>>>(facc,out);
}

// Round 3
// 747.468 us; speedup vs baseline: 5.9707x; 5.9707x over previous
//
#include <hip/hip_runtime.h>
#include <cstdint>

typedef __bf16 bf16_t;
typedef __attribute__((ext_vector_type(8))) __bf16 bf16x8;
typedef __attribute__((ext_vector_type(4))) __bf16 bf16x4;
typedef __attribute__((ext_vector_type(4))) float f32x4;

#define MFMA16(a,b,c) __builtin_amdgcn_mfma_f32_16x16x32_bf16((a),(b),(c),0,0,0)

// ---------------- workspace offsets (float units) ----------------
constexpr size_t o_wcatT = 0;                    // bf16 [448][768]
constexpr size_t o_whfT  = o_wcatT + 172032;     // bf16 [128][256]
constexpr size_t o_whvT  = o_whfT  + 16384;      // bf16 [128][512]
constexpr size_t o_WvT   = o_whvT  + 32768;      // bf16 [512][256]
constexpr size_t o_whh   = o_WvT   + 65536;      // f32  [64][66]
constexpr size_t o_keyb  = o_whh   + 4224;       // bf16 [B*T*1024][64]
constexpr size_t o_ms    = o_keyb  + 1048576;    // f32  [B*T*1024]
constexpr size_t o_qeb   = o_ms    + 32768;      // bf16 [B*T*1024][64]
constexpr size_t o_f16b  = o_qeb   + 1048576;    // bf16 [B*T*1024][256]
constexpr size_t o_qfb   = o_f16b  + 4194304;    // bf16 [B*T*1024][160]
constexpr size_t o_kfb   = o_qfb   + 2621440;    // bf16 [B*3072][160]
constexpr size_t o_vb    = o_kfb   + 491520;     // bf16 [B*3072][512]
constexpr size_t o_vhT   = o_vb    + 1572864;    // bf16 [B][128][3072]
constexpr size_t o_s5    = o_vhT   + 393216;     // bf16 [B][5][1024][3072]
constexpr size_t o_pv    = o_s5    + 15728640;   // f32  [B][5][1024][72]
constexpr size_t o_p16   = o_pv    + 737280;     // bf16 [B*T*1024][72]
constexpr size_t o_mh    = o_p16   + 1179648;    // f32  [B][15][1024][66]
constexpr size_t o_hid   = o_mh    + 2027520;    // f32  [B][1024][64]
constexpr size_t o_wmk   = o_hid   + 131072;     // f32  [B][1024]
constexpr size_t ws_need = o_wmk   + 2048;

// ---------------- init: transposed bf16 weight panels ----------------
__global__ __launch_bounds__(256)
void k_init(const float* __restrict__ Wk, const float* __restrict__ Wsh,
            const float* __restrict__ Wse, const float* __restrict__ Wf,
            const float* __restrict__ Wv, const float* __restrict__ Whd,
            const float* __restrict__ Wdec,
            bf16_t* __restrict__ wcatT, bf16_t* __restrict__ whfT,
            bf16_t* __restrict__ whvT, bf16_t* __restrict__ WvT,
            float* __restrict__ whh)
{
    int idx = blockIdx.x*256 + threadIdx.x;
    if (idx < 344064) {                       // wcatT[n][k] n<448 k<768
        int n = idx/768, k = idx%768;
        float v = 0.f;
        if (n < 64)       v = Wk[k*64+n];
        else if (n == 64) v = Wsh[k];
        else if (n < 129) v = Wse[k*64+(n-65)];
        else if (n < 385) v = Wf[k*256+(n-129)];
        wcatT[idx] = (bf16_t)v;
        return;
    }
    idx -= 344064;
    if (idx < 32768) {                        // whfT[c][k] c<128 k<256
        int c = idx/256, k = idx%256;
        float v = 0.f;
        if (c < 64) v = Whd[k*64+c]; else if (c == 64) v = Wdec[k];
        whfT[idx] = (bf16_t)v;
        return;
    }
    idx -= 32768;
    if (idx < 65536) {                        // whvT[c][k] c<128 k<512
        int c = idx/512, k = idx%512;
        float v = 0.f;
        if (c < 64) v = Whd[(256+k)*64+c]; else if (c == 64) v = Wdec[256+k];
        whvT[idx] = (bf16_t)v;
        return;
    }
    idx -= 65536;
    if (idx < 131072) {                       // WvT[n][k] n<512 k<256
        int n = idx/256, k = idx%256;
        WvT[idx] = (bf16_t)Wv[k*512+n];
        return;
    }
    idx -= 131072;
    if (idx < 4224) {                         // whh[k][c] (stride 66), c<65 real
        int k = idx/66, c = idx%66;
        float v = 0.f;
        if (c < 64) v = Whd[(768+k)*64+c]; else if (c == 64) v = Wdec[768+k];
        whh[idx] = v;
    }
}

// ---------------- projection GEMM (MFMA, fused patchify) ----------------
// grid (7, 16, 32), block 256. C[1024,448] = patches[1024,768] @ wcatT^T
__global__ __launch_bounds__(256)
void k_proj(const float* __restrict__ frames, const bf16_t* __restrict__ wcatT,
            bf16_t* __restrict__ keyb, float* __restrict__ msb,
            bf16_t* __restrict__ qeb, bf16_t* __restrict__ f16b)
{
    const int bt = blockIdx.z;
    const int n0 = blockIdx.x*64, p0 = blockIdx.y*64;
    const int tid = threadIdx.x;
    const int lane = tid & 63, w = tid >> 6;
    const int wr = w >> 1, wc = w & 1;
    const int l15 = lane & 15, l4 = lane >> 4;
    __shared__ __align__(16) bf16_t Al[64][40];
    f32x4 acc[2][2] = {};
    const float* fb = frames + (size_t)bt*786432;
    const int srow = tid >> 2, skg = tid & 3;
    const int p = p0 + srow, pi_ = p >> 5, pj_ = p & 31;

    for (int k0 = 0; k0 < 768; k0 += 32) {
        int k = k0 + skg*8;
        int c = k >> 8, rem = k & 255, qi = rem >> 4, qj = rem & 15;
        const float* src = fb + (size_t)c*262144 + (size_t)(pi_*16 + qi)*512 + pj_*16 + qj;
        float4 v0 = *(const float4*)src;
        float4 v1 = *(const float4*)(src + 4);
        __syncthreads();
        bf16x8 pk;
        pk[0]=(bf16_t)v0.x; pk[1]=(bf16_t)v0.y; pk[2]=(bf16_t)v0.z; pk[3]=(bf16_t)v0.w;
        pk[4]=(bf16_t)v1.x; pk[5]=(bf16_t)v1.y; pk[6]=(bf16_t)v1.z; pk[7]=(bf16_t)v1.w;
        *(bf16x8*)&Al[srow][skg*8] = pk;
        __syncthreads();
        bf16x8 a0 = *(const bf16x8*)&Al[wr*32 + l15][l4*8];
        bf16x8 a1 = *(const bf16x8*)&Al[wr*32 + 16 + l15][l4*8];
        bf16x8 b0 = *(const bf16x8*)(wcatT + (size_t)(n0 + wc*32 + l15)*768 + k0 + l4*8);
        bf16x8 b1 = *(const bf16x8*)(wcatT + (size_t)(n0 + wc*32 + 16 + l15)*768 + k0 + l4*8);
        acc[0][0] = MFMA16(a0, b0, acc[0][0]);
        acc[0][1] = MFMA16(a0, b1, acc[0][1]);
        acc[1][0] = MFMA16(a1, b0, acc[1][0]);
        acc[1][1] = MFMA16(a1, b1, acc[1][1]);
    }
    #pragma unroll
    for (int fi = 0; fi < 2; fi++)
    #pragma unroll
    for (int fj = 0; fj < 2; fj++)
    #pragma unroll
    for (int r = 0; r < 4; r++) {
        int pp = p0 + wr*32 + fi*16 + l4*4 + r;
        int nn = n0 + wc*32 + fj*16 + l15;
        float v = acc[fi][fj][r];
        size_t rowb = (size_t)bt*1024 + pp;
        if (nn < 64)       keyb[rowb*64 + nn] = (bf16_t)v;
        else if (nn == 64) msb[rowb] = v*v + 1.f;
        else if (nn < 129) qeb[rowb*64 + (nn-65)] = (bf16_t)(1.f/(1.f+expf(-v)));
        else if (nn < 385) f16b[rowb*256 + (nn-129)] = (bf16_t)v;
    }
}

// ---------------- Qfeat: [qe*qk | qe | b_sq | zeros] bf16 ----------------
// grid (32, 128), block (64,8)
__global__ __launch_bounds__(512)
void k_qf(const bf16_t* __restrict__ keyb, const bf16_t* __restrict__ qeb,
          bf16_t* __restrict__ qfb)
{
    int bt = blockIdx.x;
    int p = blockIdx.y*8 + threadIdx.y;
    int c = threadIdx.x;
    size_t rowb = (size_t)bt*1024 + p;
    float qk = (float)keyb[rowb*64 + c];
    float qv = (float)qeb[rowb*64 + c];
    float bsq = qv*qk*qk;
    #pragma unroll
    for (int off = 32; off; off >>= 1) bsq += __shfl_xor(bsq, off);
    bf16_t* q = qfb + rowb*160;
    q[c]      = (bf16_t)(qv*qk);
    q[64 + c] = (bf16_t)qv;
    if (c == 0) q[128] = (bf16_t)bsq;
    if (c < 31) q[129 + c] = (bf16_t)0.f;
}

// ---------------- Kfeat rows for a memory slot ----------------
// grid (2, 128), block (64,8)
__global__ __launch_bounds__(512)
void k_kf(const bf16_t* __restrict__ keyb, const float* __restrict__ msb,
          bf16_t* __restrict__ kfb, int tm, int slot)
{
    int b = blockIdx.x;
    int p = blockIdx.y*8 + threadIdx.y;
    int c = threadIdx.x;
    size_t rowb = (size_t)(b*16 + tm)*1024 + p;
    float mk = (float)keyb[rowb*64 + c];
    float m  = msb[rowb];
    bf16_t* kr = kfb + ((size_t)b*3072 + slot*1024 + p)*160;
    kr[c]      = (bf16_t)( m*mk*0.25f);
    kr[64 + c] = (bf16_t)(-m*mk*mk*0.125f);
    if (c == 0) kr[128] = (bf16_t)(-m*0.125f);
    if (c < 31) kr[129 + c] = (bf16_t)0.f;
}

// ---------------- t=0 mask: aggregate + 16x16 avg-pool ----------------
__global__ __launch_bounds__(256)
void k_mask0(const float* __restrict__ im, float* __restrict__ wmask)
{
    int idx = blockIdx.x*256 + threadIdx.x;
    int b = idx >> 10, p = idx & 1023;
    int i = p >> 5, j = p & 31;
    const float* mb = im + (size_t)b*262144 + (size_t)(i*16)*512 + j*16;
    float s = 0.f;
    for (int pi = 0; pi < 16; pi++)
        for (int pj = 0; pj < 16; pj++) {
            float m = mb[pi*512 + pj];
            float p1 = fminf(fmaxf(m,      1e-7f), 1.f-1e-7f);
            float q1 = fminf(fmaxf(1.f-m,  1e-7f), 1.f-1e-7f);
            float l1 = logf(p1/(1.f-p1));
            float l0 = logf(q1/(1.f-q1));
            s += 1.f/(1.f+expf(l0-l1));
        }
    wmask[idx] = s*(1.f/256.f);
}

// ---------------- value (MFMA): V = f16 @ Wv[0:256] + wmask*Wv[256] ----------------
// grid (8, 16, 2), block 256
__global__ __launch_bounds__(256)
void k_value(const bf16_t* __restrict__ f16b, const float* __restrict__ wmk,
             const bf16_t* __restrict__ WvT, const float* __restrict__ Wv,
             bf16_t* __restrict__ vb, int t, int slot)
{
    int b = blockIdx.z;
    int n0 = blockIdx.x*64, p0 = blockIdx.y*64;
    const int tid = threadIdx.x, lane = tid & 63, w = tid >> 6;
    const int wr = w >> 1, wc = w & 1, l15 = lane & 15, l4 = lane >> 4;
    const bf16_t* A = f16b + ((size_t)(b*16 + t)*1024 + p0)*256;
    f32x4 acc[2][2] = {};
    int ar = wr*32 + l15, bc = n0 + wc*32 + l15, koff = l4*8;
    #pragma unroll
    for (int ks = 0; ks < 8; ks++) {
        bf16x8 a0 = *(const bf16x8*)(A + (size_t)ar*256 + ks*32 + koff);
        bf16x8 a1 = *(const bf16x8*)(A + (size_t)(ar+16)*256 + ks*32 + koff);
        bf16x8 b0 = *(const bf16x8*)(WvT + (size_t)bc*256 + ks*32 + koff);
        bf16x8 b1 = *(const bf16x8*)(WvT + (size_t)(bc+16)*256 + ks*32 + koff);
        acc[0][0] = MFMA16(a0, b0, acc[0][0]);
        acc[0][1] = MFMA16(a0, b1, acc[0][1]);
        acc[1][0] = MFMA16(a1, b0, acc[1][0]);
        acc[1][1] = MFMA16(a1, b1, acc[1][1]);
    }
    #pragma unroll
    for (int fi = 0; fi < 2; fi++)
    #pragma unroll
    for (int fj = 0; fj < 2; fj++) {
        int nn = n0 + wc*32 + fj*16 + l15;
        float wvl = Wv[131072 + nn];
        #pragma unroll
        for (int r = 0; r < 4; r++) {
            int pp = p0 + wr*32 + fi*16 + l4*4 + r;
            float wm = wmk[b*1024 + pp];
            vb[((size_t)b*3072 + slot*1024 + pp)*512 + nn] = (bf16_t)(acc[fi][fj][r] + wm*wvl);
        }
    }
}

// ---------------- Vh^T (MFMA): vhT[c][n] = (V @ [Whd_mid|Wdec_mid])[n][c] ----------------
// grid (16, 2), block 256, tile 64(n) x 128(c)
__global__ __launch_bounds__(256)
void k_vh(const bf16_t* __restrict__ vb, const bf16_t* __restrict__ whvT,
          bf16_t* __restrict__ vhT, int slot)
{
    int b = blockIdx.y;
    int n0 = blockIdx.x*64;
    const int tid = threadIdx.x, lane = tid & 63, w = tid >> 6;
    const int wr = w >> 1, wc = w & 1, l15 = lane & 15, l4 = lane >> 4;
    const bf16_t* A = vb + ((size_t)b*3072 + slot*1024 + n0)*512;
    f32x4 acc[2][4] = {};
    int ar = wr*32 + l15, koff = l4*8;
    #pragma unroll 4
    for (int ks = 0; ks < 16; ks++) {
        bf16x8 a0 = *(const bf16x8*)(A + (size_t)ar*512 + ks*32 + koff);
        bf16x8 a1 = *(const bf16x8*)(A + (size_t)(ar+16)*512 + ks*32 + koff);
        #pragma unroll
        for (int fj = 0; fj < 4; fj++) {
            int cc = wc*64 + fj*16 + l15;
            bf16x8 bv = *(const bf16x8*)(whvT + (size_t)cc*512 + ks*32 + koff);
            acc[0][fj] = MFMA16(a0, bv, acc[0][fj]);
            acc[1][fj] = MFMA16(a1, bv, acc[1][fj]);
        }
    }
    #pragma unroll
    for (int fi = 0; fi < 2; fi++)
    #pragma unroll
    for (int fj = 0; fj < 4; fj++) {
        int cc = wc*64 + fj*16 + l15;
        if (cc < 65) {
            #pragma unroll
            for (int r = 0; r < 4; r++) {
                int nn = n0 + wr*32 + fi*16 + l4*4 + r;
                vhT[(size_t)b*393216 + (size_t)cc*3072 + slot*1024 + nn] = (bf16_t)acc[fi][fj][r];
            }
        }
    }
}

// ---------------- pre16 (MFMA): f16 @ [Whd_lo|Wdec_lo] -> [p][65] ----------------
// grid (16, 32), block 256, tile 64 x 128
__global__ __launch_bounds__(256)
void k_pre16(const bf16_t* __restrict__ f16b, const bf16_t* __restrict__ whfT,
             bf16_t* __restrict__ p16b)
{
    int bt = blockIdx.y;
    int p0 = blockIdx.x*64;
    const int tid = threadIdx.x, lane = tid & 63, w = tid >> 6;
    const int wr = w >> 1, wc = w & 1, l15 = lane & 15, l4 = lane >> 4;
    const bf16_t* A = f16b + ((size_t)bt*1024 + p0)*256;
    f32x4 acc[2][4] = {};
    int ar = wr*32 + l15, koff = l4*8;
    #pragma unroll
    for (int ks = 0; ks < 8; ks++) {
        bf16x8 a0 = *(const bf16x8*)(A + (size_t)ar*256 + ks*32 + koff);
        bf16x8 a1 = *(const bf16x8*)(A + (size_t)(ar+16)*256 + ks*32 + koff);
        #pragma unroll
        for (int fj = 0; fj < 4; fj++) {
            int cc = wc*64 + fj*16 + l15;
            bf16x8 bv = *(const bf16x8*)(whfT + (size_t)cc*256 + ks*32 + koff);
            acc[0][fj] = MFMA16(a0, bv, acc[0][fj]);
            acc[1][fj] = MFMA16(a1, bv, acc[1][fj]);
        }
    }
    #pragma unroll
    for (int fi = 0; fi < 2; fi++)
    #pragma unroll
    for (int fj = 0; fj < 4; fj++) {
        int cc = wc*64 + fj*16 + l15;
        if (cc < 65) {
            #pragma unroll
            for (int r = 0; r < 4; r++) {
                int pp = p0 + wr*32 + fi*16 + l4*4 + r;
                p16b[((size_t)bt*1024 + pp)*72 + cc] = (bf16_t)acc[fi][fj][r];
            }
        }
    }
}

// ---------------- S (MFMA): S5[b][ts] = qf @ kf^T ----------------
// grid (N/64, 16, 10), block 256
__global__ __launch_bounds__(256)
void k_s(const bf16_t* __restrict__ qfb, const bf16_t* __restrict__ kfb,
         bf16_t* __restrict__ S5, int t0)
{
    int bz = blockIdx.z;
    int b = bz/5, ts = bz%5, t = t0 + ts;
    int n0 = blockIdx.x*64, p0 = blockIdx.y*64;
    const int tid = threadIdx.x, lane = tid & 63, w = tid >> 6;
    const int wr = w >> 1, wc = w & 1, l15 = lane & 15, l4 = lane >> 4;
    const bf16_t* A = qfb + ((size_t)(b*16 + t)*1024 + p0)*160;
    const bf16_t* B = kfb + ((size_t)b*3072 + n0)*160;
    f32x4 acc[2][2] = {};
    int ar = wr*32 + l15, bc = wc*32 + l15, koff = l4*8;
    #pragma unroll
    for (int ks = 0; ks < 5; ks++) {
        bf16x8 a0 = *(const bf16x8*)(A + (size_t)ar*160 + ks*32 + koff);
        bf16x8 a1 = *(const bf16x8*)(A + (size_t)(ar+16)*160 + ks*32 + koff);
        bf16x8 b0 = *(const bf16x8*)(B + (size_t)bc*160 + ks*32 + koff);
        bf16x8 b1 = *(const bf16x8*)(B + (size_t)(bc+16)*160 + ks*32 + koff);
        acc[0][0] = MFMA16(a0, b0, acc[0][0]);
        acc[0][1] = MFMA16(a0, b1, acc[0][1]);
        acc[1][0] = MFMA16(a1, b0, acc[1][0]);
        acc[1][1] = MFMA16(a1, b1, acc[1][1]);
    }
    bf16_t* So = S5 + ((size_t)bz*1024 + p0)*3072 + n0;
    #pragma unroll
    for (int fi = 0; fi < 2; fi++)
    #pragma unroll
    for (int fj = 0; fj < 2; fj++)
    #pragma unroll
    for (int r = 0; r < 4; r++) {
        int pp = wr*32 + fi*16 + l4*4 + r;
        int nn = wc*32 + fj*16 + l15;
        So[(size_t)pp*3072 + nn] = (bf16_t)acc[fi][fj][r];
    }
}

// ---------------- fused row softmax in-place: S -> P = exp(S-max)/sum ----------------
// grid (1024, 5, 2), block 256
__global__ __launch_bounds__(256)
void k_smax(bf16_t* __restrict__ S5, int N)
{
    int p = blockIdx.x, ts = blockIdx.y, b = blockIdx.z;
    int tid = threadIdx.x, lane = tid & 63, w = tid >> 6;
    bf16_t* row = S5 + ((size_t)((b*5 + ts)*1024) + p)*3072;
    __shared__ float red[4];
    int nv = N >> 10;              // 1..3 vectors of 4 per thread
    float v[12];
    float mx = -1e30f;
    for (int i = 0; i < nv; i++) {
        bf16x4 x = *(const bf16x4*)(row + i*1024 + tid*4);
        #pragma unroll
        for (int j = 0; j < 4; j++) { v[i*4+j] = (float)x[j]; mx = fmaxf(mx, v[i*4+j]); }
    }
    #pragma unroll
    for (int off = 1; off < 64; off <<= 1) mx = fmaxf(mx, __shfl_xor(mx, off));
    if (lane == 0) red[w] = mx;
    __syncthreads();
    mx = fmaxf(fmaxf(red[0], red[1]), fmaxf(red[2], red[3]));
    float sum = 0.f;
    for (int i = 0; i < nv*4; i++) { v[i] = expf(v[i] - mx); sum += v[i]; }
    #pragma unroll
    for (int off = 1; off < 64; off <<= 1) sum += __shfl_xor(sum, off);
    __syncthreads();
    if (lane == 0) red[w] = sum;
    __syncthreads();
    float rinv = 1.f/(red[0] + red[1] + red[2] + red[3]);
    for (int i = 0; i < nv; i++) {
        bf16x4 x;
        #pragma unroll
        for (int j = 0; j < 4; j++) x[j] = (bf16_t)(v[i*4+j]*rinv);
        *(bf16x4*)(row + i*1024 + tid*4) = x;
    }
}

// ---------------- PV (MFMA): PV[b][ts][p][0:65] = P @ vhT^T ----------------
// grid (16, 5, 2), block 256, tile 64 x 128
__global__ __launch_bounds__(256)
void k_r(const bf16_t* __restrict__ S5, const bf16_t* __restrict__ vhT,
         float* __restrict__ PV, int N)
{
    int b = blockIdx.z, ts = blockIdx.y, p0 = blockIdx.x*64;
    const int tid = threadIdx.x, lane = tid & 63, w = tid >> 6;
    const int wr = w >> 1, wc = w & 1, l15 = lane & 15, l4 = lane >> 4;
    const bf16_t* A = S5 + ((size_t)((b*5 + ts)*1024) + p0)*3072;
    const bf16_t* Bv = vhT + (size_t)b*393216;
    f32x4 acc[2][4] = {};
    int ar = wr*32 + l15, koff = l4*8;
    #pragma unroll 2
    for (int k0 = 0; k0 < N; k0 += 32) {
        bf16x8 a0 = *(const bf16x8*)(A + (size_t)ar*3072 + k0 + koff);
        bf16x8 a1 = *(const bf16x8*)(A + (size_t)(ar+16)*3072 + k0 + koff);
        #pragma unroll
        for (int fj = 0; fj < 4; fj++) {
            int cc = wc*64 + fj*16 + l15;
            bf16x8 bv = *(const bf16x8*)(Bv + (size_t)cc*3072 + k0 + koff);
            acc[0][fj] = MFMA16(a0, bv, acc[0][fj]);
            acc[1][fj] = MFMA16(a1, bv, acc[1][fj]);
        }
    }
    float* O = PV + ((size_t)((b*5 + ts)*1024) + p0)*72;
    #pragma unroll
    for (int fi = 0; fi < 2; fi++)
    #pragma unroll
    for (int fj = 0; fj < 4; fj++) {
        int cc = wc*64 + fj*16 + l15;
        if (cc < 65) {
            #pragma unroll
            for (int r = 0; r < 4; r++) {
                int pp = wr*32 + fi*16 + l4*4 + r;
                O[(size_t)pp*72 + cc] = acc[fi][fj][r];
            }
        }
    }
}

// ---------------- sequential 5-step chain, one row per wave ----------------
// grid (256, 2), block 256
__global__ __launch_bounds__(256)
void k_chain2(const bf16_t* __restrict__ p16b, const float* __restrict__ PV,
              const float* __restrict__ whhbuf, float* __restrict__ hidden,
              float* __restrict__ wmk, float* __restrict__ mh, int t0, int ph)
{
    int b = blockIdx.y;
    int tid = threadIdx.x, lane = tid & 63, w = tid >> 6;
    int p = blockIdx.x*4 + w;
    __shared__ float whh_s[64][66];
    __shared__ float hid_s[4][64];
    for (int idx = tid; idx < 64*66; idx += 256) whh_s[idx/66][idx%66] = whhbuf[idx];
    float h = hidden[((size_t)b*1024 + p)*64 + lane];
    hid_s[w][lane] = h;
    __syncthreads();
    float wd = whh_s[lane][64];
    for (int ts = 0; ts < 5; ts++) {
        int t = t0 + ts;
        size_t r16 = ((size_t)(b*16 + t)*1024 + p)*72;
        size_t rpv = ((size_t)((b*5 + ts)*1024) + p)*72;
        float pre   = (float)p16b[r16 + lane] + PV[rpv + lane];
        float fgpre = (float)p16b[r16 + 64]   + PV[rpv + 64];
        float s = pre;
        #pragma unroll 8
        for (int k = 0; k < 64; k++) s += hid_s[w][k]*whh_s[k][lane];
        float hl = tanhf(s);
        float fgs = hl*wd;
        #pragma unroll
        for (int off = 1; off < 64; off <<= 1) fgs += __shfl_xor(fgs, off);
        float fg = fgpre + fgs;
        float m = 1.f/(1.f+expf(-fg));
        size_t rmh = ((size_t)(b*15 + ph*5 + ts)*1024 + p)*66;
        mh[rmh + lane] = m*hl;
        if (lane == 0) mh[rmh + 64] = m;
        if (ts == 4 && lane == 0) wmk[b*1024 + p] = m;
        h = hl;
        __syncthreads();
        hid_s[w][lane] = h;
        __syncthreads();
    }
    hidden[((size_t)b*1024 + p)*64 + lane] = h;
}

// ---------------- hidden GEMM (f32 SIMT, small): tanh([V|hid?] @ Wh2) ----------------
// grid (1, 16, 2), block 256
__global__ __launch_bounds__(256)
void k_hid(const bf16_t* __restrict__ vb, const float* __restrict__ Wh2,
           float* __restrict__ hidden, int vslot, int has_h)
{
    int b = blockIdx.z; int p0 = blockIdx.y*64;
    int tid = threadIdx.x, tx = tid & 15, ty = tid >> 4;
    __shared__ float As[16][68], Bs[16][68];
    float acc[4][4] = {};
    const bf16_t* A = vb + ((size_t)b*3072 + vslot*1024)*512;
    const float* Hh = hidden + (size_t)b*1024*64;
    int KK = has_h ? 576 : 512;
    const int kk = tid & 15, rr = tid >> 4, colB = tid & 63, kB = tid >> 6;
    for (int k0 = 0; k0 < KK; k0 += 16) {
        #pragma unroll
        for (int s = 0; s < 4; s++) {
            int row = rr + s*16, p = p0 + row, k = k0 + kk;
            As[kk][row] = (k < 512) ? (float)A[(size_t)p*512 + k] : Hh[(size_t)p*64 + (k-512)];
        }
        #pragma unroll
        for (int s = 0; s < 4; s++) { int kb2 = kB + s*4; Bs[kb2][colB] = Wh2[(size_t)(k0+kb2)*64 + colB]; }
        __syncthreads();
        #pragma unroll
        for (int q = 0; q < 16; q++) {
            float4 av = *(const float4*)&As[q][ty*4];
            float4 bv = *(const float4*)&Bs[q][tx*4];
            float a_[4] = {av.x,av.y,av.z,av.w};
            float b_[4] = {bv.x,bv.y,bv.z,bv.w};
            #pragma unroll
            for (int i = 0; i < 4; i++)
                #pragma unroll
                for (int j = 0; j < 4; j++)
                    acc[i][j] = fmaf(a_[i], b_[j], acc[i][j]);
        }
        __syncthreads();
    }
    #pragma unroll
    for (int i = 0; i < 4; i++) {
        int p = p0 + ty*4 + i;
        #pragma unroll
        for (int j = 0; j < 4; j++)
            hidden[(size_t)(b*1024 + p)*64 + tx*4 + j] = tanhf(acc[i][j]);
    }
}

// ---------------- feat t=0: mean over spatial of key ----------------
__global__ void k_feat0(const bf16_t* __restrict__ keyb, float* __restrict__ out)
{
    int b = blockIdx.x, c = threadIdx.x;
    const bf16_t* kb = keyb + (size_t)(b*16)*1024*64;
    float s = 0.f;
    for (int p = 0; p < 1024; p++) s += (float)kb[(size_t)p*64 + c];
    out[(size_t)(b*16)*64 + c] = s*(1.f/1024.f);
}

// ---------------- feats t=1..15: weighted mean reduce ----------------
// grid (15, 2), block 128
__global__ __launch_bounds__(128)
void k_feats(const float* __restrict__ mh, float* __restrict__ out)
{
    int slot = blockIdx.x, b = blockIdx.y, t = slot + 1;
    int tid = threadIdx.x;
    __shared__ float ms_s;
    const float* base = mh + (size_t)(b*15 + slot)*1024*66;
    float s = 0.f;
    if (tid < 64) {
        for (int p = 0; p < 1024; p++) s += base[(size_t)p*66 + tid];
    } else if (tid == 64) {
        float q = 0.f;
        for (int p = 0; p < 1024; p++) q += base[(size_t)p*66 + 64];
        ms_s = q;
    }
    __syncthreads();
    if (tid < 64) out[(size_t)(b*16 + t)*64 + tid] = s / fmaxf(ms_s, 1e-6f);
}

// ---------------- host launcher ----------------
extern "C" void kernel_launch(void* const* d_in, const int* in_sizes, int n_in,
                              void* d_out, int out_size, void* d_ws, size_t ws_size,
                              hipStream_t stream)
{
    (void)in_sizes; (void)n_in; (void)out_size;
    if (ws_size < ws_need*sizeof(float)) return;
    const float* frames = (const float*)d_in[0];
    const float* imask  = (const float*)d_in[1];
    const float* Wk   = (const float*)d_in[3];
    const float* Wsh  = (const float*)d_in[4];
    const float* Wse  = (const float*)d_in[5];
    const float* Wf   = (const float*)d_in[6];
    const float* Wv   = (const float*)d_in[7];
    const float* Wh2  = (const float*)d_in[8];
    const float* Whd  = (const float*)d_in[9];
    const float* Wdec = (const float*)d_in[10];
    float* out = (float*)d_out;
    float* ws  = (float*)d_ws;

    bf16_t* wcatT = (bf16_t*)(ws + o_wcatT);
    bf16_t* whfT  = (bf16_t*)(ws + o_whfT);
    bf16_t* whvT  = (bf16_t*)(ws + o_whvT);
    bf16_t* WvT   = (bf16_t*)(ws + o_WvT);
    float*  whh   = ws + o_whh;
    bf16_t* keyb  = (bf16_t*)(ws + o_keyb);
    float*  msb   = ws + o_ms;
    bf16_t* qeb   = (bf16_t*)(ws + o_qeb);
    bf16_t* f16b  = (bf16_t*)(ws + o_f16b);
    bf16_t* qfb   = (bf16_t*)(ws + o_qfb);
    bf16_t* kfb   = (bf16_t*)(ws + o_kfb);
    bf16_t* vb    = (bf16_t*)(ws + o_vb);
    bf16_t* vhT   = (bf16_t*)(ws + o_vhT);
    bf16_t* S5    = (bf16_t*)(ws + o_s5);
    float*  PV    = ws + o_pv;
    bf16_t* p16b  = (bf16_t*)(ws + o_p16);
    float*  mh    = ws + o_mh;
    float*  hid   = ws + o_hid;
    float*  wmk   = ws + o_wmk;

    k_init<<<2257, 256, 0, stream>>>(Wk, Wsh, Wse, Wf, Wv, Whd, Wdec,
                                     wcatT, whfT, whvT, WvT, whh);
    k_proj<<<dim3(7,16,32), 256, 0, stream>>>(frames, wcatT, keyb, msb, qeb, f16b);
    k_qf<<<dim3(32,128), dim3(64,8), 0, stream>>>(keyb, qeb, qfb);
    k_mask0<<<8, 256, 0, stream>>>(imask, wmk);
    k_kf<<<dim3(2,128), dim3(64,8), 0, stream>>>(keyb, msb, kfb, 0, 0);
    k_value<<<dim3(8,16,2), 256, 0, stream>>>(f16b, wmk, WvT, Wv, vb, 0, 0);
    k_vh<<<dim3(16,2), 256, 0, stream>>>(vb, whvT, vhT, 0);
    k_hid<<<dim3(1,16,2), 256, 0, stream>>>(vb, Wh2, hid, 0, 0);
    k_feat0<<<2, 64, 0, stream>>>(keyb, out);
    k_pre16<<<dim3(16,32), 256, 0, stream>>>(f16b, whfT, p16b);

    const int Ns[3] = {1024, 2048, 3072};
    for (int ph = 0; ph < 3; ph++) {
        int t0 = 1 + ph*5, N = Ns[ph];
        k_s<<<dim3(N/64,16,10), 256, 0, stream>>>(qfb, kfb, S5, t0);
        k_smax<<<dim3(1024,5,2), 256, 0, stream>>>(S5, N);
        k_r<<<dim3(16,5,2), 256, 0, stream>>>(S5, vhT, PV, N);
        k_chain2<<<dim3(256,2), 256, 0, stream>>>(p16b, PV, whh, hid, wmk, mh, t0, ph);
        if (ph < 2) {
            int tm = t0 + 4, slot = ph + 1;
            k_kf<<<dim3(2,128), dim3(64,8), 0, stream>>>(keyb, msb, kfb, tm, slot);
            k_value<<<dim3(8,16,2), 256, 0, stream>>>(f16b, wmk, WvT, Wv, vb, tm, slot);
            k_vh<<<dim3(16,2), 256, 0, stream>>>(vb, whvT, vhT, slot);
            if (ph == 1) k_hid<<<dim3(1,16,2), 256, 0, stream>>>(vb, Wh2, hid, 2, 1);
        }
    }
    k_feats<<<dim3(15,2), 128, 0, stream>>>(mh, out);
}